// Round 8
// baseline (338.161 us; speedup 1.0000x reference)
//
#include <hip/hip_runtime.h>
#include <hip/hip_bf16.h>
#include <math.h>

typedef unsigned short u16;
typedef unsigned int   u32;

#define CC 512
#define NN 196
#define TT 4
#define BB 32
#define TBB 128
#define NHH 8
#define HD 64

// compact-row layout: row = tb*196 + n, M = 128*196 = 25088 rows
#define ROWS_T  6272                      // rows per t-slice (32*196)
#define CSTRIDE ((size_t)ROWS_T * CC)     // elems per t-slice = 3,211,264

typedef __attribute__((ext_vector_type(8))) _Float16 f16x8;
typedef __attribute__((ext_vector_type(4))) float f32x4;

#define ONE_H 0x3C00            // fp16 1.0

__device__ __forceinline__ u16 h_bits(_Float16 h) { return *(u16*)&h; }
__device__ __forceinline__ float h2f(u16 u) { return (float)(*(const _Float16*)&u); }
__device__ __forceinline__ u32 pk2(u16 a, u16 b) { return (u32)a | ((u32)b << 16); }

// async 16B/lane global->LDS; lds base must be wave-uniform
__device__ __forceinline__ void gld16(const void* g, void* l) {
    __builtin_amdgcn_global_load_lds(
        (const __attribute__((address_space(1))) void*)g,
        (__attribute__((address_space(3))) void*)l, 16, 0, 0);
}

// ---------------- merged prep: W 2-plane fp16 split (blocks 0..4095) + BN folds (4096..4103) ----------------
__global__ __launch_bounds__(256) void k_prep(
    const float* __restrict__ qw, const float* __restrict__ kw,
    const float* __restrict__ vw, const float* __restrict__ pw,
    const float* __restrict__ cb0, const float* __restrict__ bg0, const float* __restrict__ bb0,
    const float* __restrict__ bm0, const float* __restrict__ bv0,
    const float* __restrict__ cb1, const float* __restrict__ bg1, const float* __restrict__ bb1,
    const float* __restrict__ bm1, const float* __restrict__ bv1,
    const float* __restrict__ cb2, const float* __restrict__ bg2, const float* __restrict__ bb2,
    const float* __restrict__ bm2, const float* __restrict__ bv2,
    const float* __restrict__ cb3, const float* __restrict__ bg3, const float* __restrict__ bb3,
    const float* __restrict__ bm3, const float* __restrict__ bv3,
    u16* __restrict__ W2, float* __restrict__ SS, float* __restrict__ SH) {
    if (blockIdx.x < 4096) {
        size_t idx = (size_t)blockIdx.x * 256 + threadIdx.x;   // 4 * 262144
        int g = (int)(idx >> 18);
        size_t rem = idx & 262143;
        const float* Ws = (g == 0) ? qw : (g == 1) ? kw : (g == 2) ? vw : pw;
        float w  = Ws[rem];
        _Float16 h0 = (fabsf(w) < 6.2e-5f) ? (_Float16)0.0f : (_Float16)w;
        float r = (w - (float)h0) * 2048.0f;   // exact; |r| <= |w| -> fp16-normal range
        _Float16 h1 = (_Float16)r;
        size_t base = (size_t)g * 524288 + rem;
        W2[base] = h_bits(h0); W2[base + 262144] = h_bits(h1);
        return;
    }
    int idx = (blockIdx.x - 4096) * 256 + threadIdx.x;   // 0..2047
    int g = idx >> 9, o = idx & 511;
    const float* cb = g == 0 ? cb0 : g == 1 ? cb1 : g == 2 ? cb2 : cb3;
    const float* bg = g == 0 ? bg0 : g == 1 ? bg1 : g == 2 ? bg2 : bg3;
    const float* bb = g == 0 ? bb0 : g == 1 ? bb1 : g == 2 ? bb2 : bb3;
    const float* bm = g == 0 ? bm0 : g == 1 ? bm1 : g == 2 ? bm2 : bm3;
    const float* bv = g == 0 ? bv0 : g == 1 ? bv1 : g == 2 ? bv2 : bv3;
    float inv = bg[o] / sqrtf(bv[o] + 1e-5f);
    SS[g * 512 + o] = inv;
    SH[g * 512 + o] = (cb[o] - bm[o]) * inv + bb[o];
}

// ---------------- head LIF + transpose: x[t][b][C][196] -> XS[tb*196+n][C] fp16 spikes (compact) ----------------
__global__ __launch_bounds__(256) void k_head_lif(const float* __restrict__ x, u16* __restrict__ XS) {
    __shared__ float T[64][65];
    const int tid = threadIdx.x;
    const int n0 = blockIdx.x * 64;       // 0..3 * 64
    const int b  = blockIdx.y;            // 0..31
    const int c_base = blockIdx.z * 64;   // 0..7 * 64
    const int c_l = tid >> 4;             // 0..15
    const int n4  = (tid & 15) * 4;       // 0..60
    const bool lv = (n0 + n4) < NN;
    const int n_r = tid >> 2;             // 0..63
    const int cq  = (tid & 3) * 16;
    const bool wv = (n0 + n_r) < NN;

    float v[4][4];
    #pragma unroll
    for (int k = 0; k < 4; ++k)
        #pragma unroll
        for (int j = 0; j < 4; ++j) v[k][j] = 0.f;

    for (int t = 0; t < TT; ++t) {
        const size_t xb = ((size_t)(t * BB + b) * CC + c_base) * NN;
        float s[4][4];
        #pragma unroll
        for (int k = 0; k < 4; ++k) {
            const int c = c_l + 16 * k;
            float4 xv = make_float4(0.f, 0.f, 0.f, 0.f);
            if (lv) xv = *(const float4*)(x + xb + (size_t)c * NN + n0 + n4);
            float xa[4] = {xv.x, xv.y, xv.z, xv.w};
            #pragma unroll
            for (int j = 0; j < 4; ++j) {
                float h = v[k][j] + (xa[j] - v[k][j]) * 0.5f;
                s[k][j] = (h >= 1.f) ? 1.f : 0.f;
                v[k][j] = (h >= 1.f) ? 0.f : h;
            }
        }
        __syncthreads();
        #pragma unroll
        for (int k = 0; k < 4; ++k)
            #pragma unroll
            for (int j = 0; j < 4; ++j) T[c_l + 16 * k][n4 + j] = s[k][j];
        __syncthreads();
        if (wv) {
            const size_t ob = ((size_t)(t * BB + b) * NN + n0 + n_r) * CC + c_base + cq;
            u16 u[16];
            #pragma unroll
            for (int m = 0; m < 16; ++m) u[m] = (T[cq + m][n_r] != 0.f) ? ONE_H : 0;
            uint4 q0 = make_uint4(pk2(u[0],u[1]),  pk2(u[2],u[3]),  pk2(u[4],u[5]),  pk2(u[6],u[7]));
            uint4 q1 = make_uint4(pk2(u[8],u[9]),  pk2(u[10],u[11]),pk2(u[12],u[13]),pk2(u[14],u[15]));
            *(uint4*)(XS + ob)     = q0;
            *(uint4*)(XS + ob + 8) = q1;
        }
        __syncthreads();
    }
}

// ---------------- fused QKV GEMM + BN + LIF -> spikes, 2-plane fp16, BK=64 ----------------
// M-tile = 4t x 32rr where rr = b*196+n is the compact row (LIF chain is per (rr,c) over t).
// Grid split into two 1176-block launches via `bias` (diagnostic: lowers top-5 cutoff to ~52us);
// per-block behavior identical to the single 2352-block launch.
__global__ __launch_bounds__(256) void k_gemm_qkv(const u16* __restrict__ S, const u16* __restrict__ W2,
                                                  const float* __restrict__ scale, const float* __restrict__ shift,
                                                  u16* __restrict__ QS, u16* __restrict__ KS, u16* __restrict__ VS,
                                                  const float* __restrict__ PW, const float* __restrict__ PL,
                                                  const float* __restrict__ PB, int bias) {
    __shared__ __align__(16) u16 smem[24576];       // 48 KB: Xt[8192] + Wt[2][8192]; reused as LY in epilogue
    u16* Xt  = smem;
    u16* WtF = smem + 8192;
    const int tid  = threadIdx.x;
    const int lane = tid & 63;
    const int w    = tid >> 6;
    const int bid  = blockIdx.x + bias;
    const int work = (bid & 7) * 294 + (bid >> 3);   // 2352 = 8 * 294, bijective XCD swizzle
    const int rrt  = work / 12;                      // 0..195 (rr0 = rrt*32)
    const int gw   = work - rrt * 12;
    const int g    = gw >> 2;                        // 0..2 (q,k,v)
    const int wtile = gw & 3;                        // 0..3 (output col block of 128)
    const int rr0  = rrt * 32;
    const u16* Wb = W2 + (size_t)g * 524288 + (size_t)(wtile * 128) * CC;
    const float* scl = scale + g * 512;
    const float* shf = shift + g * 512;

    const int lrow8  = lane >> 3;                    // 0..7 (staging row within 8)
    const int gchunk = ((lane & 7) ^ lrow8) * 8;     // swizzled logical chunk (elems)
    const int l15 = lane & 15;
    const int q4  = lane >> 4;                       // 0..3
    const int wm = (w >> 1) * 64, wn = (w & 1) * 64;

    // wave w stages tile rows [w*32, w*32+32) == time step t=w, rr = rr0 + i*8 + lrow8
    const size_t arow0 = (size_t)w * CSTRIDE + (size_t)rr0 * CC;

    f32x4 acc[4][4];
    f32x4 zz = {0.f, 0.f, 0.f, 0.f};
    #pragma unroll
    for (int i = 0; i < 4; ++i)
        #pragma unroll
        for (int j = 0; j < 4; ++j) acc[i][j] = zz;

    for (int c0 = 0; c0 < CC; c0 += 64) {
        __syncthreads();
        #pragma unroll
        for (int i = 0; i < 4; ++i) {                // spikes: 4 instrs/wave, rows t=w
            int p = w * 4 + i;                       // tile rows p*8..p*8+7
            gld16(S + arow0 + (size_t)(i * 8 + lrow8) * CC + c0 + gchunk, &Xt[p * 512]);
        }
        #pragma unroll
        for (int i = 0; i < 8; ++i) {                // W: 8 instrs/wave
            int lin = w * 8 + i;                     // 0..31
            int s = lin >> 4, p = lin & 15;
            gld16(Wb + (size_t)s * 262144 + (size_t)(p * 8 + lrow8) * CC + c0 + gchunk,
                  WtF + s * 8192 + p * 512);
        }
        __syncthreads();

        #pragma unroll
        for (int ks = 0; ks < 2; ++ks) {
            const int cpo = ((ks * 4 + q4) ^ (l15 & 7)) * 8;
            f16x8 sf[4], sflo[4];
            #pragma unroll
            for (int i = 0; i < 4; ++i) {
                sf[i]   = *(const f16x8*)&Xt[(wm + i * 16 + l15) * 64 + cpo];
                sflo[i] = sf[i] * (_Float16)0.00048828125f;   // 2^-11
            }
            #pragma unroll
            for (int s = 0; s < 2; ++s) {
                f16x8 wf[4];
                #pragma unroll
                for (int i = 0; i < 4; ++i)
                    wf[i] = *(const f16x8*)&WtF[s * 8192 + (wn + i * 16 + l15) * 64 + cpo];
                #pragma unroll
                for (int mt = 0; mt < 4; ++mt)
                    #pragma unroll
                    for (int nt = 0; nt < 4; ++nt)
                        acc[mt][nt] = __builtin_amdgcn_mfma_f32_16x16x32_f16(
                            s ? sflo[mt] : sf[mt], wf[nt], acc[mt][nt], 0, 0, 0);
            }
        }
    }

    // ---- fused BN + LIF epilogue ----
    const float pwv = (g == 0) ? log1pf(expf(PW[0])) : 0.f;
    const float plv = (g == 0) ? log1pf(expf(PL[0])) : 0.f;
    const float pbv = (g == 0) ? PB[0] : 0.f;
    u16* OUT = (g == 0) ? QS : (g == 1) ? KS : VS;
    float* LY = (float*)smem;                 // [2 pair][128 row][33]
    const int pairid = w & 1;
    const int pr  = tid >> 7;                 // chain pair-region 0..1
    const int idx = tid & 127;

    #pragma unroll
    for (int cc = 0; cc < 2; ++cc) {          // column half within each pair's 64
        __syncthreads();                      // staging LDS dead / prev chains done
        #pragma unroll
        for (int ntl = 0; ntl < 2; ++ntl) {
            const int nt = cc * 2 + ntl;
            const int o  = wtile * 128 + wn + nt * 16 + l15;
            const float sc = scl[o], sh = shf[o];
            const int col32 = ntl * 16 + l15;
            #pragma unroll
            for (int mt = 0; mt < 4; ++mt) {
                const int tr0 = wm + mt * 16 + q4 * 4;
                #pragma unroll
                for (int r = 0; r < 4; ++r)
                    LY[(pairid * 128 + tr0 + r) * 33 + col32] = acc[mt][nt][r] * sc + sh;
            }
        }
        __syncthreads();
        #pragma unroll
        for (int stp = 0; stp < 4; ++stp) {
            const int chain = stp * 128 + idx;        // 0..511
            const int nn  = chain >> 4;
            const int c2  = (chain & 15) * 2;         // even col within 32
            const int rr  = rr0 + nn;
            const float* Lp = &LY[(pr * 128 + nn) * 33 + c2];
            float ya[4][2];
            #pragma unroll
            for (int t = 0; t < 4; ++t) {
                ya[t][0] = Lp[t * 32 * 33];
                ya[t][1] = Lp[t * 32 * 33 + 1];
            }
            const int ocol = wtile * 128 + pr * 64 + cc * 32 + c2;
            u32* op = (u32*)(OUT + (size_t)rr * CC + ocol);
            if (g == 0) {
                float von[2] = {0.f, 0.f}, voff[2] = {0.f, 0.f}, vpp[2] = {0.f, 0.f};
                #pragma unroll
                for (int t = 0; t < 4; ++t) {
                    u16 sp2[2];
                    #pragma unroll
                    for (int j = 0; j < 2; ++j) {
                        float qv = ya[t][j], h;
                        h = von[j]  + ( qv - von[j] ) * 0.5f; bool s1 = (h >= 1.f); von[j]  = s1 ? 0.f : h;
                        h = voff[j] + (-qv - voff[j]) * 0.5f; bool s2 = (h >= 1.f); voff[j] = s2 ? 0.f : h;
                        float diff = pwv * (s1 ? 1.f : 0.f) - plv * (s2 ? 1.f : 0.f) + pbv;
                        h = vpp[j] + (diff - vpp[j]) * 0.5f; bool sp = (h >= 1.f); vpp[j] = sp ? 0.f : h;
                        sp2[j] = sp ? ONE_H : 0;
                    }
                    op[t * (CSTRIDE / 2)] = pk2(sp2[0], sp2[1]);
                }
            } else {
                float vm[2] = {0.f, 0.f};
                #pragma unroll
                for (int t = 0; t < 4; ++t) {
                    u16 s2[2];
                    #pragma unroll
                    for (int j = 0; j < 2; ++j) {
                        float h = vm[j] + (ya[t][j] - vm[j]) * 0.5f;
                        bool s = (h >= 1.f); vm[j] = s ? 0.f : h;
                        s2[j] = s ? ONE_H : 0;
                    }
                    op[t * (CSTRIDE / 2)] = pk2(s2[0], s2[1]);
                }
            }
        }
    }
}

// ---------------- MFMA attention per (tb,h): kv = K^T V ; O = 0.125 * Q_pp kv -> fp16 compact ----------------
// (R2/R4 configuration: 1024 blocks, strides 136/72, 39.2 KB LDS -> 4 blocks/CU)
__global__ __launch_bounds__(256) void k_attn(const u16* __restrict__ Q, const u16* __restrict__ K,
                                              const u16* __restrict__ V, u16* __restrict__ OS) {
    __shared__ __align__(16) u16 sm[19584];   // max(2*64*136, 208*72 + 64*72) u16 = 39168 B
    u16* Kt  = sm;            // phase A: [64 d][136]
    u16* Vt  = sm + 8704;     // phase A: [64 e][136]
    u16* Qs  = sm;            // phase B: [208 n][72]
    u16* kvT = sm + 14976;    // phase B: [64 e][72]

    const int tid = threadIdx.x;
    const int tb  = blockIdx.x >> 3;
    const int h   = blockIdx.x & 7;
    const size_t gb = (size_t)tb * NN * CC + (size_t)h * HD;

    const int srow = tid >> 2;            // 0..63 staging row
    const int sdq  = (tid & 3) * 16;      // 0,16,32,48

    const int lane = tid & 63;
    const int w    = tid >> 6;
    const int l15  = lane & 15;
    const int kb8  = (lane >> 4) * 8;
    const int quad = (lane >> 4) * 4;
    const int dh = (w >> 1) * 32, eh = (w & 1) * 32;

    f32x4 accA[2][2];
    f32x4 zz = {0.f, 0.f, 0.f, 0.f};
    #pragma unroll
    for (int i = 0; i < 2; ++i)
        #pragma unroll
        for (int j = 0; j < 2; ++j) accA[i][j] = zz;

    const uint4 z4 = make_uint4(0, 0, 0, 0);

    // ---- phase A over 2 n-chunks of 128
    #pragma unroll
    for (int ch = 0; ch < 2; ++ch) {
        if (ch) __syncthreads();
        #pragma unroll
        for (int c = 0; c < 2; ++c) {
            int n  = ch * 128 + c * 64 + srow;
            int nl = c * 64 + srow;
            bool valid = n < NN;
            const u16* kr = K + gb + (size_t)n * CC + sdq;
            const u16* vr = V + gb + (size_t)n * CC + sdq;
            uint4 ka  = valid ? *(const uint4*)kr : z4;
            uint4 kb2 = valid ? *(const uint4*)(kr + 8) : z4;
            uint4 va  = valid ? *(const uint4*)vr : z4;
            uint4 vb2 = valid ? *(const uint4*)(vr + 8) : z4;
            u32 kwv[8] = {ka.x, ka.y, ka.z, ka.w, kb2.x, kb2.y, kb2.z, kb2.w};
            u32 vwv[8] = {va.x, va.y, va.z, va.w, vb2.x, vb2.y, vb2.z, vb2.w};
            #pragma unroll
            for (int i = 0; i < 8; ++i) {
                Kt[(sdq + 2 * i) * 136 + nl]     = (u16)(kwv[i] & 0xFFFF);
                Kt[(sdq + 2 * i + 1) * 136 + nl] = (u16)(kwv[i] >> 16);
                Vt[(sdq + 2 * i) * 136 + nl]     = (u16)(vwv[i] & 0xFFFF);
                Vt[(sdq + 2 * i + 1) * 136 + nl] = (u16)(vwv[i] >> 16);
            }
        }
        __syncthreads();
        #pragma unroll
        for (int k0 = 0; k0 < 128; k0 += 32) {
            f16x8 af[2], bv[2];
            #pragma unroll
            for (int i = 0; i < 2; ++i) {
                af[i] = *(const f16x8*)&Kt[(dh + i * 16 + l15) * 136 + k0 + kb8];
                bv[i] = *(const f16x8*)&Vt[(eh + i * 16 + l15) * 136 + k0 + kb8];
            }
            #pragma unroll
            for (int i = 0; i < 2; ++i)
                #pragma unroll
                for (int j = 0; j < 2; ++j)
                    accA[i][j] = __builtin_amdgcn_mfma_f32_16x16x32_f16(af[i], bv[j], accA[i][j], 0, 0, 0);
        }
    }
    __syncthreads();   // all waves done with Kt/Vt before overwrite

    // ---- write kv^T (fp16, exact: integers <= 196) and stage Q
    #pragma unroll
    for (int i = 0; i < 2; ++i)
        #pragma unroll
        for (int j = 0; j < 2; ++j)
            #pragma unroll
            for (int r = 0; r < 4; ++r) {
                int e = eh + j * 16 + l15;
                int d = dh + i * 16 + quad + r;
                _Float16 hv = (_Float16)accA[i][j][r];
                kvT[e * 72 + d] = h_bits(hv);
            }
    #pragma unroll
    for (int p = 0; p < 4; ++p) {
        int n = p * 64 + srow;
        if (n < 208) {
            if (n < NN) {
                const u16* qr = Q + gb + (size_t)n * CC + sdq;
                uint4 qa  = *(const uint4*)qr;
                uint4 qb2 = *(const uint4*)(qr + 8);
                u32 qwv[8] = {qa.x, qa.y, qa.z, qa.w, qb2.x, qb2.y, qb2.z, qb2.w};
                #pragma unroll
                for (int i = 0; i < 8; ++i) {
                    Qs[n * 72 + sdq + 2 * i]     = (u16)(qwv[i] & 0xFFFF);
                    Qs[n * 72 + sdq + 2 * i + 1] = (u16)(qwv[i] >> 16);
                }
            } else {
                #pragma unroll
                for (int i = 0; i < 16; ++i) Qs[n * 72 + sdq + i] = 0;
            }
        }
    }
    __syncthreads();

    // ---- phase B: wave w owns e-tile [w*16, w*16+16)
    f16x8 bq0 = *(const f16x8*)&kvT[(w * 16 + l15) * 72 + 0  + kb8];
    f16x8 bq1 = *(const f16x8*)&kvT[(w * 16 + l15) * 72 + 32 + kb8];
    u16* ob = OS + (size_t)tb * NN * CC + (size_t)h * HD + w * 16 + l15;
    #pragma unroll
    for (int nt = 0; nt < 13; ++nt) {
        f32x4 acc = zz;
        f16x8 a0 = *(const f16x8*)&Qs[(nt * 16 + l15) * 72 + 0  + kb8];
        f16x8 a1 = *(const f16x8*)&Qs[(nt * 16 + l15) * 72 + 32 + kb8];
        acc = __builtin_amdgcn_mfma_f32_16x16x32_f16(a0, bq0, acc, 0, 0, 0);
        acc = __builtin_amdgcn_mfma_f32_16x16x32_f16(a1, bq1, acc, 0, 0, 0);
        #pragma unroll
        for (int r = 0; r < 4; ++r) {
            int n = nt * 16 + quad + r;
            if (n < NN) {
                _Float16 ov = (_Float16)(acc[r] * 0.125f);
                ob[(size_t)n * CC] = h_bits(ov);
            }
        }
    }
}

// ---------------- attn LIF (vth=0.5), compact flat, in place on fp16 ----------------
__global__ __launch_bounds__(256) void k_attn_lif(uint4* __restrict__ OS) {
    const size_t idx = (size_t)blockIdx.x * 256 + threadIdx.x;   // uint4-group index per t-slice
    float v[8];
    #pragma unroll
    for (int j = 0; j < 8; ++j) v[j] = 0.f;
    #pragma unroll
    for (int t = 0; t < TT; ++t) {
        const size_t o8 = idx + (size_t)t * (CSTRIDE / 8);
        uint4 d = OS[o8];
        u32 dw[4] = {d.x, d.y, d.z, d.w};
        u16 u[8];
        #pragma unroll
        for (int p = 0; p < 4; ++p) {
            #pragma unroll
            for (int hf = 0; hf < 2; ++hf) {
                int j = p * 2 + hf;
                u16 raw = hf ? (u16)(dw[p] >> 16) : (u16)(dw[p] & 0xFFFF);
                float xv = h2f(raw);
                float h = v[j] + (xv - v[j]) * 0.5f;
                bool s = (h >= 0.5f);
                v[j] = s ? 0.f : h;
                u[j] = s ? ONE_H : 0;
            }
        }
        OS[o8] = make_uint4(pk2(u[0],u[1]), pk2(u[2],u[3]), pk2(u[4],u[5]), pk2(u[6],u[7]));
    }
}

// ---------------- final projection GEMM: out[tb][o][n], compact rows, 2-plane fp16, BK=64 ----------------
__global__ __launch_bounds__(256) void k_gemm_proj(const u16* __restrict__ S, const u16* __restrict__ W2,
                                                   const float* __restrict__ scale, const float* __restrict__ shift,
                                                   float* __restrict__ Y) {
    __shared__ __align__(16) u16 Xt[128 * 64];
    __shared__ __align__(16) u16 Wt[2][128 * 64];
    const int tid  = threadIdx.x;
    const int lane = tid & 63;
    const int w    = tid >> 6;
    const int bid  = blockIdx.x;
    const int work = (bid & 7) * 98 + (bid >> 3);
    const int ntile = work >> 2;    // 0..195
    const int wtile = work & 3;     // 0..3
    const u16* Sb = S + (size_t)ntile * 128 * CC;
    const u16* Wb = W2 + (size_t)(wtile * 128) * CC;

    const int lrow8  = lane >> 3;
    const int gchunk = ((lane & 7) ^ lrow8) * 8;
    const int l15 = lane & 15;
    const int q4  = lane >> 4;
    const int wm = (w >> 1) * 64, wn = (w & 1) * 64;

    // a 128-row tile crosses at most one tb boundary
    const int tb0 = (ntile * 128) / NN;
    const int bnd = (tb0 + 1) * NN;

    f32x4 acc[4][4];
    f32x4 zz = {0.f, 0.f, 0.f, 0.f};
    #pragma unroll
    for (int i = 0; i < 4; ++i)
        #pragma unroll
        for (int j = 0; j < 4; ++j) acc[i][j] = zz;

    for (int c0 = 0; c0 < CC; c0 += 64) {
        __syncthreads();
        #pragma unroll
        for (int i = 0; i < 4; ++i) {
            int p = w * 4 + i;
            gld16(Sb + (size_t)(p * 8 + lrow8) * CC + c0 + gchunk, &Xt[p * 512]);
        }
        #pragma unroll
        for (int i = 0; i < 8; ++i) {
            int lin = w * 8 + i;
            int s = lin >> 4, p = lin & 15;
            gld16(Wb + (size_t)s * 262144 + (size_t)(p * 8 + lrow8) * CC + c0 + gchunk,
                  &Wt[s][p * 512]);
        }
        __syncthreads();

        #pragma unroll
        for (int ks = 0; ks < 2; ++ks) {
            const int cpo = ((ks * 4 + q4) ^ (l15 & 7)) * 8;
            f16x8 sf[4], sflo[4];
            #pragma unroll
            for (int i = 0; i < 4; ++i) {
                sf[i]   = *(const f16x8*)&Xt[(wn + i * 16 + l15) * 64 + cpo];
                sflo[i] = sf[i] * (_Float16)0.00048828125f;   // 2^-11
            }
            #pragma unroll
            for (int s = 0; s < 2; ++s) {
                f16x8 wf[4];
                #pragma unroll
                for (int i = 0; i < 4; ++i)
                    wf[i] = *(const f16x8*)&Wt[s][(wm + i * 16 + l15) * 64 + cpo];
                #pragma unroll
                for (int mt = 0; mt < 4; ++mt)
                    #pragma unroll
                    for (int nt = 0; nt < 4; ++nt)
                        acc[mt][nt] = __builtin_amdgcn_mfma_f32_16x16x32_f16(
                            wf[mt], s ? sflo[nt] : sf[nt], acc[mt][nt], 0, 0, 0);
            }
        }
    }

    #pragma unroll
    for (int mt = 0; mt < 4; ++mt) {
        int o0 = wtile * 128 + wm + mt * 16 + (lane >> 4) * 4;
        #pragma unroll
        for (int nt = 0; nt < 4; ++nt) {
            int row = ntile * 128 + wn + nt * 16 + l15;
            int tb = (row >= bnd) ? tb0 + 1 : tb0;
            int n  = row - tb * NN;
            #pragma unroll
            for (int r = 0; r < 4; ++r)
                Y[((size_t)tb * CC + o0 + r) * NN + n] = acc[mt][nt][r] * scale[o0 + r] + shift[o0 + r];
        }
    }
}

extern "C" void kernel_launch(void* const* d_in, const int* in_sizes, int n_in,
                              void* d_out, int out_size, void* d_ws, size_t ws_size,
                              hipStream_t stream) {
    const float* x    = (const float*)d_in[0];
    const float* q_cw = (const float*)d_in[1];
    const float* q_cb = (const float*)d_in[2];
    const float* q_bg = (const float*)d_in[3];
    const float* q_bb = (const float*)d_in[4];
    const float* q_bm = (const float*)d_in[5];
    const float* q_bv = (const float*)d_in[6];
    const float* k_cw = (const float*)d_in[7];
    const float* k_cb = (const float*)d_in[8];
    const float* k_bg = (const float*)d_in[9];
    const float* k_bb = (const float*)d_in[10];
    const float* k_bm = (const float*)d_in[11];
    const float* k_bv = (const float*)d_in[12];
    const float* v_cw = (const float*)d_in[13];
    const float* v_cb = (const float*)d_in[14];
    const float* v_bg = (const float*)d_in[15];
    const float* v_bb = (const float*)d_in[16];
    const float* v_bm = (const float*)d_in[17];
    const float* v_bv = (const float*)d_in[18];
    const float* p_cw = (const float*)d_in[19];
    const float* p_cb = (const float*)d_in[20];
    const float* p_bg = (const float*)d_in[21];
    const float* p_bb = (const float*)d_in[22];
    const float* p_bm = (const float*)d_in[23];
    const float* p_bv = (const float*)d_in[24];
    const float* pshw = (const float*)d_in[25];
    const float* pllw = (const float*)d_in[26];
    const float* ppb  = (const float*)d_in[27];
    float* out = (float*)d_out;

    // ws map:
    //   [0,26)    XS head spikes (25.7MB)
    //   [27,53)   QS pp spikes
    //   [78,104)  OS attn fp16 (pre/post LIF, in place)
    //   [182,208) KS ; [208,234) VS
    //   [234,238) W2 (4MB) ; then SS/SH
    if (ws_size < (size_t)242 * 1024 * 1024) return;
    char* W = (char*)d_ws;
    u16*   XS = (u16*)W;
    u16*   QS = (u16*)(W + ((size_t)27 << 20));
    u16*   OS = (u16*)(W + ((size_t)78 << 20));
    u16*   KS = (u16*)(W + ((size_t)182 << 20));
    u16*   VS = (u16*)(W + ((size_t)208 << 20));
    u16*   W2 = (u16*)(W + ((size_t)234 << 20));
    float* SS = (float*)(W + ((size_t)238 << 20));            // scale[4][512]
    float* SH = SS + 2048;                                     // shift[4][512]

    k_prep<<<4104, 256, 0, stream>>>(q_cw, k_cw, v_cw, p_cw,
                                     q_cb, q_bg, q_bb, q_bm, q_bv,
                                     k_cb, k_bg, k_bb, k_bm, k_bv,
                                     v_cb, v_bg, v_bb, v_bm, v_bv,
                                     p_cb, p_bg, p_bb, p_bm, p_bv, W2, SS, SH);

    k_head_lif<<<dim3(4, 32, 8), 256, 0, stream>>>(x, XS);

    // fused QKV projection + BN + LIF, split into two half-grid launches (diagnostic:
    // lowers the rocprof top-5 cutoff to ~52us so the true #2/#3 kernels become visible)
    k_gemm_qkv<<<1176, 256, 0, stream>>>(XS, W2, SS, SH, QS, KS, VS, pshw, pllw, ppb, 0);
    k_gemm_qkv<<<1176, 256, 0, stream>>>(XS, W2, SS, SH, QS, KS, VS, pshw, pllw, ppb, 1176);

    // split attention (R4 config): per (tb,h), 1024 blocks, 4 blocks/CU
    k_attn<<<TBB * NHH, 256, 0, stream>>>(QS, KS, VS, OS);
    k_attn_lif<<<1568, 256, 0, stream>>>((uint4*)OS);

    k_gemm_proj<<<784, 256, 0, stream>>>(OS, W2 + 3 * 524288, SS + 1536, SH + 1536, out);
}

// Round 9
// 320.357 us; speedup vs baseline: 1.0556x; 1.0556x over previous
//
#include <hip/hip_runtime.h>
#include <hip/hip_bf16.h>
#include <math.h>

typedef unsigned short u16;
typedef unsigned int   u32;

#define CC 512
#define NN 196
#define TT 4
#define BB 32
#define TBB 128
#define NHH 8
#define HD 64

// compact-row layout: row = tb*196 + n, M = 128*196 = 25088 rows
#define ROWS_T  6272                      // rows per t-slice (32*196)
#define CSTRIDE ((size_t)ROWS_T * CC)     // elems per t-slice = 3,211,264

typedef __attribute__((ext_vector_type(8))) _Float16 f16x8;
typedef __attribute__((ext_vector_type(4))) float f32x4;

#define ONE_H 0x3C00            // fp16 1.0

__device__ __forceinline__ u16 h_bits(_Float16 h) { return *(u16*)&h; }
__device__ __forceinline__ float h2f(u16 u) { return (float)(*(const _Float16*)&u); }
__device__ __forceinline__ u32 pk2(u16 a, u16 b) { return (u32)a | ((u32)b << 16); }

// async 16B/lane global->LDS; lds base must be wave-uniform
__device__ __forceinline__ void gld16(const void* g, void* l) {
    __builtin_amdgcn_global_load_lds(
        (const __attribute__((address_space(1))) void*)g,
        (__attribute__((address_space(3))) void*)l, 16, 0, 0);
}

// ---------------- merged prep: W 2-plane fp16 split (blocks 0..4095) + BN folds (4096..4103) ----------------
__global__ __launch_bounds__(256) void k_prep(
    const float* __restrict__ qw, const float* __restrict__ kw,
    const float* __restrict__ vw, const float* __restrict__ pw,
    const float* __restrict__ cb0, const float* __restrict__ bg0, const float* __restrict__ bb0,
    const float* __restrict__ bm0, const float* __restrict__ bv0,
    const float* __restrict__ cb1, const float* __restrict__ bg1, const float* __restrict__ bb1,
    const float* __restrict__ bm1, const float* __restrict__ bv1,
    const float* __restrict__ cb2, const float* __restrict__ bg2, const float* __restrict__ bb2,
    const float* __restrict__ bm2, const float* __restrict__ bv2,
    const float* __restrict__ cb3, const float* __restrict__ bg3, const float* __restrict__ bb3,
    const float* __restrict__ bm3, const float* __restrict__ bv3,
    u16* __restrict__ W2, float* __restrict__ SS, float* __restrict__ SH) {
    if (blockIdx.x < 4096) {
        size_t idx = (size_t)blockIdx.x * 256 + threadIdx.x;   // 4 * 262144
        int g = (int)(idx >> 18);
        size_t rem = idx & 262143;
        const float* Ws = (g == 0) ? qw : (g == 1) ? kw : (g == 2) ? vw : pw;
        float w  = Ws[rem];
        _Float16 h0 = (fabsf(w) < 6.2e-5f) ? (_Float16)0.0f : (_Float16)w;
        float r = (w - (float)h0) * 2048.0f;   // exact; |r| <= |w| -> fp16-normal range
        _Float16 h1 = (_Float16)r;
        size_t base = (size_t)g * 524288 + rem;
        W2[base] = h_bits(h0); W2[base + 262144] = h_bits(h1);
        return;
    }
    int idx = (blockIdx.x - 4096) * 256 + threadIdx.x;   // 0..2047
    int g = idx >> 9, o = idx & 511;
    const float* cb = g == 0 ? cb0 : g == 1 ? cb1 : g == 2 ? cb2 : cb3;
    const float* bg = g == 0 ? bg0 : g == 1 ? bg1 : g == 2 ? bg2 : bg3;
    const float* bb = g == 0 ? bb0 : g == 1 ? bb1 : g == 2 ? bb2 : bb3;
    const float* bm = g == 0 ? bm0 : g == 1 ? bm1 : g == 2 ? bm2 : bm3;
    const float* bv = g == 0 ? bv0 : g == 1 ? bv1 : g == 2 ? bv2 : bv3;
    float inv = bg[o] / sqrtf(bv[o] + 1e-5f);
    SS[g * 512 + o] = inv;
    SH[g * 512 + o] = (cb[o] - bm[o]) * inv + bb[o];
}

// ---------------- head LIF + transpose: x[t][b][C][196] -> XS[tb*196+n][C] fp16 spikes (compact) ----------------
__global__ __launch_bounds__(256) void k_head_lif(const float* __restrict__ x, u16* __restrict__ XS) {
    __shared__ float T[64][65];
    const int tid = threadIdx.x;
    const int n0 = blockIdx.x * 64;       // 0..3 * 64
    const int b  = blockIdx.y;            // 0..31
    const int c_base = blockIdx.z * 64;   // 0..7 * 64
    const int c_l = tid >> 4;             // 0..15
    const int n4  = (tid & 15) * 4;       // 0..60
    const bool lv = (n0 + n4) < NN;
    const int n_r = tid >> 2;             // 0..63
    const int cq  = (tid & 3) * 16;
    const bool wv = (n0 + n_r) < NN;

    float v[4][4];
    #pragma unroll
    for (int k = 0; k < 4; ++k)
        #pragma unroll
        for (int j = 0; j < 4; ++j) v[k][j] = 0.f;

    for (int t = 0; t < TT; ++t) {
        const size_t xb = ((size_t)(t * BB + b) * CC + c_base) * NN;
        float s[4][4];
        #pragma unroll
        for (int k = 0; k < 4; ++k) {
            const int c = c_l + 16 * k;
            float4 xv = make_float4(0.f, 0.f, 0.f, 0.f);
            if (lv) xv = *(const float4*)(x + xb + (size_t)c * NN + n0 + n4);
            float xa[4] = {xv.x, xv.y, xv.z, xv.w};
            #pragma unroll
            for (int j = 0; j < 4; ++j) {
                float h = v[k][j] + (xa[j] - v[k][j]) * 0.5f;
                s[k][j] = (h >= 1.f) ? 1.f : 0.f;
                v[k][j] = (h >= 1.f) ? 0.f : h;
            }
        }
        __syncthreads();
        #pragma unroll
        for (int k = 0; k < 4; ++k)
            #pragma unroll
            for (int j = 0; j < 4; ++j) T[c_l + 16 * k][n4 + j] = s[k][j];
        __syncthreads();
        if (wv) {
            const size_t ob = ((size_t)(t * BB + b) * NN + n0 + n_r) * CC + c_base + cq;
            u16 u[16];
            #pragma unroll
            for (int m = 0; m < 16; ++m) u[m] = (T[cq + m][n_r] != 0.f) ? ONE_H : 0;
            uint4 q0 = make_uint4(pk2(u[0],u[1]),  pk2(u[2],u[3]),  pk2(u[4],u[5]),  pk2(u[6],u[7]));
            uint4 q1 = make_uint4(pk2(u[8],u[9]),  pk2(u[10],u[11]),pk2(u[12],u[13]),pk2(u[14],u[15]));
            *(uint4*)(XS + ob)     = q0;
            *(uint4*)(XS + ob + 8) = q1;
        }
        __syncthreads();
    }
}

// ---------------- fused QKV GEMM + BN + LIF -> spikes, 2-plane fp16, BK=64 ----------------
// M-tile = 4t x 32rr where rr = b*196+n is the compact row (LIF chain is per (rr,c) over t).
__global__ __launch_bounds__(256) void k_gemm_qkv(const u16* __restrict__ S, const u16* __restrict__ W2,
                                                  const float* __restrict__ scale, const float* __restrict__ shift,
                                                  u16* __restrict__ QS, u16* __restrict__ KS, u16* __restrict__ VS,
                                                  const float* __restrict__ PW, const float* __restrict__ PL,
                                                  const float* __restrict__ PB) {
    __shared__ __align__(16) u16 smem[24576];       // 48 KB: Xt[8192] + Wt[2][8192]; reused as LY in epilogue
    u16* Xt  = smem;
    u16* WtF = smem + 8192;
    const int tid  = threadIdx.x;
    const int lane = tid & 63;
    const int w    = tid >> 6;
    const int bid  = blockIdx.x;
    const int work = (bid & 7) * 294 + (bid >> 3);   // 2352 = 8 * 294, bijective XCD swizzle
    const int rrt  = work / 12;                      // 0..195 (rr0 = rrt*32)
    const int gw   = work - rrt * 12;
    const int g    = gw >> 2;                        // 0..2 (q,k,v)
    const int wtile = gw & 3;                        // 0..3 (output col block of 128)
    const int rr0  = rrt * 32;
    const u16* Wb = W2 + (size_t)g * 524288 + (size_t)(wtile * 128) * CC;
    const float* scl = scale + g * 512;
    const float* shf = shift + g * 512;

    const int lrow8  = lane >> 3;                    // 0..7 (staging row within 8)
    const int gchunk = ((lane & 7) ^ lrow8) * 8;     // swizzled logical chunk (elems)
    const int l15 = lane & 15;
    const int q4  = lane >> 4;                       // 0..3
    const int wm = (w >> 1) * 64, wn = (w & 1) * 64;

    // wave w stages tile rows [w*32, w*32+32) == time step t=w, rr = rr0 + i*8 + lrow8
    const size_t arow0 = (size_t)w * CSTRIDE + (size_t)rr0 * CC;

    f32x4 acc[4][4];
    f32x4 zz = {0.f, 0.f, 0.f, 0.f};
    #pragma unroll
    for (int i = 0; i < 4; ++i)
        #pragma unroll
        for (int j = 0; j < 4; ++j) acc[i][j] = zz;

    for (int c0 = 0; c0 < CC; c0 += 64) {
        __syncthreads();
        #pragma unroll
        for (int i = 0; i < 4; ++i) {                // spikes: 4 instrs/wave, rows t=w
            int p = w * 4 + i;                       // tile rows p*8..p*8+7
            gld16(S + arow0 + (size_t)(i * 8 + lrow8) * CC + c0 + gchunk, &Xt[p * 512]);
        }
        #pragma unroll
        for (int i = 0; i < 8; ++i) {                // W: 8 instrs/wave
            int lin = w * 8 + i;                     // 0..31
            int s = lin >> 4, p = lin & 15;
            gld16(Wb + (size_t)s * 262144 + (size_t)(p * 8 + lrow8) * CC + c0 + gchunk,
                  WtF + s * 8192 + p * 512);
        }
        __syncthreads();

        #pragma unroll
        for (int ks = 0; ks < 2; ++ks) {
            const int cpo = ((ks * 4 + q4) ^ (l15 & 7)) * 8;
            f16x8 sf[4], sflo[4];
            #pragma unroll
            for (int i = 0; i < 4; ++i) {
                sf[i]   = *(const f16x8*)&Xt[(wm + i * 16 + l15) * 64 + cpo];
                sflo[i] = sf[i] * (_Float16)0.00048828125f;   // 2^-11
            }
            #pragma unroll
            for (int s = 0; s < 2; ++s) {
                f16x8 wf[4];
                #pragma unroll
                for (int i = 0; i < 4; ++i)
                    wf[i] = *(const f16x8*)&WtF[s * 8192 + (wn + i * 16 + l15) * 64 + cpo];
                #pragma unroll
                for (int mt = 0; mt < 4; ++mt)
                    #pragma unroll
                    for (int nt = 0; nt < 4; ++nt)
                        acc[mt][nt] = __builtin_amdgcn_mfma_f32_16x16x32_f16(
                            s ? sflo[mt] : sf[mt], wf[nt], acc[mt][nt], 0, 0, 0);
            }
        }
    }

    // ---- fused BN + LIF epilogue ----
    const float pwv = (g == 0) ? log1pf(expf(PW[0])) : 0.f;
    const float plv = (g == 0) ? log1pf(expf(PL[0])) : 0.f;
    const float pbv = (g == 0) ? PB[0] : 0.f;
    u16* OUT = (g == 0) ? QS : (g == 1) ? KS : VS;
    float* LY = (float*)smem;                 // [2 pair][128 row][33]
    const int pairid = w & 1;
    const int pr  = tid >> 7;                 // chain pair-region 0..1
    const int idx = tid & 127;

    #pragma unroll
    for (int cc = 0; cc < 2; ++cc) {          // column half within each pair's 64
        __syncthreads();                      // staging LDS dead / prev chains done
        #pragma unroll
        for (int ntl = 0; ntl < 2; ++ntl) {
            const int nt = cc * 2 + ntl;
            const int o  = wtile * 128 + wn + nt * 16 + l15;
            const float sc = scl[o], sh = shf[o];
            const int col32 = ntl * 16 + l15;
            #pragma unroll
            for (int mt = 0; mt < 4; ++mt) {
                const int tr0 = wm + mt * 16 + q4 * 4;
                #pragma unroll
                for (int r = 0; r < 4; ++r)
                    LY[(pairid * 128 + tr0 + r) * 33 + col32] = acc[mt][nt][r] * sc + sh;
            }
        }
        __syncthreads();
        #pragma unroll
        for (int stp = 0; stp < 4; ++stp) {
            const int chain = stp * 128 + idx;        // 0..511
            const int nn  = chain >> 4;
            const int c2  = (chain & 15) * 2;         // even col within 32
            const int rr  = rr0 + nn;
            const float* Lp = &LY[(pr * 128 + nn) * 33 + c2];
            float ya[4][2];
            #pragma unroll
            for (int t = 0; t < 4; ++t) {
                ya[t][0] = Lp[t * 32 * 33];
                ya[t][1] = Lp[t * 32 * 33 + 1];
            }
            const int ocol = wtile * 128 + pr * 64 + cc * 32 + c2;
            u32* op = (u32*)(OUT + (size_t)rr * CC + ocol);
            if (g == 0) {
                float von[2] = {0.f, 0.f}, voff[2] = {0.f, 0.f}, vpp[2] = {0.f, 0.f};
                #pragma unroll
                for (int t = 0; t < 4; ++t) {
                    u16 sp2[2];
                    #pragma unroll
                    for (int j = 0; j < 2; ++j) {
                        float qv = ya[t][j], h;
                        h = von[j]  + ( qv - von[j] ) * 0.5f; bool s1 = (h >= 1.f); von[j]  = s1 ? 0.f : h;
                        h = voff[j] + (-qv - voff[j]) * 0.5f; bool s2 = (h >= 1.f); voff[j] = s2 ? 0.f : h;
                        float diff = pwv * (s1 ? 1.f : 0.f) - plv * (s2 ? 1.f : 0.f) + pbv;
                        h = vpp[j] + (diff - vpp[j]) * 0.5f; bool sp = (h >= 1.f); vpp[j] = sp ? 0.f : h;
                        sp2[j] = sp ? ONE_H : 0;
                    }
                    op[t * (CSTRIDE / 2)] = pk2(sp2[0], sp2[1]);
                }
            } else {
                float vm[2] = {0.f, 0.f};
                #pragma unroll
                for (int t = 0; t < 4; ++t) {
                    u16 s2[2];
                    #pragma unroll
                    for (int j = 0; j < 2; ++j) {
                        float h = vm[j] + (ya[t][j] - vm[j]) * 0.5f;
                        bool s = (h >= 1.f); vm[j] = s ? 0.f : h;
                        s2[j] = s ? ONE_H : 0;
                    }
                    op[t * (CSTRIDE / 2)] = pk2(s2[0], s2[1]);
                }
            }
        }
    }
}

// ---------------- MFMA attention per (tb,h): kv = K^T V ; O = 0.125 * Q_pp kv -> fp16 compact ----------------
// (R2/R4 configuration: 1024 blocks, strides 136/72, 39.2 KB LDS -> 4 blocks/CU)
__global__ __launch_bounds__(256) void k_attn(const u16* __restrict__ Q, const u16* __restrict__ K,
                                              const u16* __restrict__ V, u16* __restrict__ OS) {
    __shared__ __align__(16) u16 sm[19584];   // max(2*64*136, 208*72 + 64*72) u16 = 39168 B
    u16* Kt  = sm;            // phase A: [64 d][136]
    u16* Vt  = sm + 8704;     // phase A: [64 e][136]
    u16* Qs  = sm;            // phase B: [208 n][72]
    u16* kvT = sm + 14976;    // phase B: [64 e][72]

    const int tid = threadIdx.x;
    const int tb  = blockIdx.x >> 3;
    const int h   = blockIdx.x & 7;
    const size_t gb = (size_t)tb * NN * CC + (size_t)h * HD;

    const int srow = tid >> 2;            // 0..63 staging row
    const int sdq  = (tid & 3) * 16;      // 0,16,32,48

    const int lane = tid & 63;
    const int w    = tid >> 6;
    const int l15  = lane & 15;
    const int kb8  = (lane >> 4) * 8;
    const int quad = (lane >> 4) * 4;
    const int dh = (w >> 1) * 32, eh = (w & 1) * 32;

    f32x4 accA[2][2];
    f32x4 zz = {0.f, 0.f, 0.f, 0.f};
    #pragma unroll
    for (int i = 0; i < 2; ++i)
        #pragma unroll
        for (int j = 0; j < 2; ++j) accA[i][j] = zz;

    const uint4 z4 = make_uint4(0, 0, 0, 0);

    // ---- phase A over 2 n-chunks of 128
    #pragma unroll
    for (int ch = 0; ch < 2; ++ch) {
        if (ch) __syncthreads();
        #pragma unroll
        for (int c = 0; c < 2; ++c) {
            int n  = ch * 128 + c * 64 + srow;
            int nl = c * 64 + srow;
            bool valid = n < NN;
            const u16* kr = K + gb + (size_t)n * CC + sdq;
            const u16* vr = V + gb + (size_t)n * CC + sdq;
            uint4 ka  = valid ? *(const uint4*)kr : z4;
            uint4 kb2 = valid ? *(const uint4*)(kr + 8) : z4;
            uint4 va  = valid ? *(const uint4*)vr : z4;
            uint4 vb2 = valid ? *(const uint4*)(vr + 8) : z4;
            u32 kwv[8] = {ka.x, ka.y, ka.z, ka.w, kb2.x, kb2.y, kb2.z, kb2.w};
            u32 vwv[8] = {va.x, va.y, va.z, va.w, vb2.x, vb2.y, vb2.z, vb2.w};
            #pragma unroll
            for (int i = 0; i < 8; ++i) {
                Kt[(sdq + 2 * i) * 136 + nl]     = (u16)(kwv[i] & 0xFFFF);
                Kt[(sdq + 2 * i + 1) * 136 + nl] = (u16)(kwv[i] >> 16);
                Vt[(sdq + 2 * i) * 136 + nl]     = (u16)(vwv[i] & 0xFFFF);
                Vt[(sdq + 2 * i + 1) * 136 + nl] = (u16)(vwv[i] >> 16);
            }
        }
        __syncthreads();
        #pragma unroll
        for (int k0 = 0; k0 < 128; k0 += 32) {
            f16x8 af[2], bv[2];
            #pragma unroll
            for (int i = 0; i < 2; ++i) {
                af[i] = *(const f16x8*)&Kt[(dh + i * 16 + l15) * 136 + k0 + kb8];
                bv[i] = *(const f16x8*)&Vt[(eh + i * 16 + l15) * 136 + k0 + kb8];
            }
            #pragma unroll
            for (int i = 0; i < 2; ++i)
                #pragma unroll
                for (int j = 0; j < 2; ++j)
                    accA[i][j] = __builtin_amdgcn_mfma_f32_16x16x32_f16(af[i], bv[j], accA[i][j], 0, 0, 0);
        }
    }
    __syncthreads();   // all waves done with Kt/Vt before overwrite

    // ---- write kv^T (fp16, exact: integers <= 196) and stage Q
    #pragma unroll
    for (int i = 0; i < 2; ++i)
        #pragma unroll
        for (int j = 0; j < 2; ++j)
            #pragma unroll
            for (int r = 0; r < 4; ++r) {
                int e = eh + j * 16 + l15;
                int d = dh + i * 16 + quad + r;
                _Float16 hv = (_Float16)accA[i][j][r];
                kvT[e * 72 + d] = h_bits(hv);
            }
    #pragma unroll
    for (int p = 0; p < 4; ++p) {
        int n = p * 64 + srow;
        if (n < 208) {
            if (n < NN) {
                const u16* qr = Q + gb + (size_t)n * CC + sdq;
                uint4 qa  = *(const uint4*)qr;
                uint4 qb2 = *(const uint4*)(qr + 8);
                u32 qwv[8] = {qa.x, qa.y, qa.z, qa.w, qb2.x, qb2.y, qb2.z, qb2.w};
                #pragma unroll
                for (int i = 0; i < 8; ++i) {
                    Qs[n * 72 + sdq + 2 * i]     = (u16)(qwv[i] & 0xFFFF);
                    Qs[n * 72 + sdq + 2 * i + 1] = (u16)(qwv[i] >> 16);
                }
            } else {
                #pragma unroll
                for (int i = 0; i < 16; ++i) Qs[n * 72 + sdq + i] = 0;
            }
        }
    }
    __syncthreads();

    // ---- phase B: wave w owns e-tile [w*16, w*16+16)
    f16x8 bq0 = *(const f16x8*)&kvT[(w * 16 + l15) * 72 + 0  + kb8];
    f16x8 bq1 = *(const f16x8*)&kvT[(w * 16 + l15) * 72 + 32 + kb8];
    u16* ob = OS + (size_t)tb * NN * CC + (size_t)h * HD + w * 16 + l15;
    #pragma unroll
    for (int nt = 0; nt < 13; ++nt) {
        f32x4 acc = zz;
        f16x8 a0 = *(const f16x8*)&Qs[(nt * 16 + l15) * 72 + 0  + kb8];
        f16x8 a1 = *(const f16x8*)&Qs[(nt * 16 + l15) * 72 + 32 + kb8];
        acc = __builtin_amdgcn_mfma_f32_16x16x32_f16(a0, bq0, acc, 0, 0, 0);
        acc = __builtin_amdgcn_mfma_f32_16x16x32_f16(a1, bq1, acc, 0, 0, 0);
        #pragma unroll
        for (int r = 0; r < 4; ++r) {
            int n = nt * 16 + quad + r;
            if (n < NN) {
                _Float16 ov = (_Float16)(acc[r] * 0.125f);
                ob[(size_t)n * CC] = h_bits(ov);
            }
        }
    }
}

// ---------------- attn LIF (vth=0.5), compact flat, in place on fp16 ----------------
// 8 fp16/thread via uint4 RMW (16B/lane both directions). Grid 1568.
__global__ __launch_bounds__(256) void k_attn_lif(uint4* __restrict__ OS) {
    const size_t idx = (size_t)blockIdx.x * 256 + threadIdx.x;   // uint4-group index per t-slice
    float v[8];
    #pragma unroll
    for (int j = 0; j < 8; ++j) v[j] = 0.f;
    #pragma unroll
    for (int t = 0; t < TT; ++t) {
        const size_t o8 = idx + (size_t)t * (CSTRIDE / 8);
        uint4 d = OS[o8];
        u32 dw[4] = {d.x, d.y, d.z, d.w};
        u16 u[8];
        #pragma unroll
        for (int p = 0; p < 4; ++p) {
            #pragma unroll
            for (int hf = 0; hf < 2; ++hf) {
                int j = p * 2 + hf;
                u16 raw = hf ? (u16)(dw[p] >> 16) : (u16)(dw[p] & 0xFFFF);
                float xv = h2f(raw);
                float h = v[j] + (xv - v[j]) * 0.5f;
                bool s = (h >= 0.5f);
                v[j] = s ? 0.f : h;
                u[j] = s ? ONE_H : 0;
            }
        }
        OS[o8] = make_uint4(pk2(u[0],u[1]), pk2(u[2],u[3]), pk2(u[4],u[5]), pk2(u[6],u[7]));
    }
}

// ---------------- final projection GEMM: out[tb][o][n], compact rows, 2-plane fp16, BK=64 ----------------
__global__ __launch_bounds__(256) void k_gemm_proj(const u16* __restrict__ S, const u16* __restrict__ W2,
                                                   const float* __restrict__ scale, const float* __restrict__ shift,
                                                   float* __restrict__ Y) {
    __shared__ __align__(16) u16 Xt[128 * 64];
    __shared__ __align__(16) u16 Wt[2][128 * 64];
    const int tid  = threadIdx.x;
    const int lane = tid & 63;
    const int w    = tid >> 6;
    const int bid  = blockIdx.x;
    const int work = (bid & 7) * 98 + (bid >> 3);
    const int ntile = work >> 2;    // 0..195
    const int wtile = work & 3;     // 0..3
    const u16* Sb = S + (size_t)ntile * 128 * CC;
    const u16* Wb = W2 + (size_t)(wtile * 128) * CC;

    const int lrow8  = lane >> 3;
    const int gchunk = ((lane & 7) ^ lrow8) * 8;
    const int l15 = lane & 15;
    const int q4  = lane >> 4;
    const int wm = (w >> 1) * 64, wn = (w & 1) * 64;

    // a 128-row tile crosses at most one tb boundary
    const int tb0 = (ntile * 128) / NN;
    const int bnd = (tb0 + 1) * NN;

    f32x4 acc[4][4];
    f32x4 zz = {0.f, 0.f, 0.f, 0.f};
    #pragma unroll
    for (int i = 0; i < 4; ++i)
        #pragma unroll
        for (int j = 0; j < 4; ++j) acc[i][j] = zz;

    for (int c0 = 0; c0 < CC; c0 += 64) {
        __syncthreads();
        #pragma unroll
        for (int i = 0; i < 4; ++i) {
            int p = w * 4 + i;
            gld16(Sb + (size_t)(p * 8 + lrow8) * CC + c0 + gchunk, &Xt[p * 512]);
        }
        #pragma unroll
        for (int i = 0; i < 8; ++i) {
            int lin = w * 8 + i;
            int s = lin >> 4, p = lin & 15;
            gld16(Wb + (size_t)s * 262144 + (size_t)(p * 8 + lrow8) * CC + c0 + gchunk,
                  &Wt[s][p * 512]);
        }
        __syncthreads();

        #pragma unroll
        for (int ks = 0; ks < 2; ++ks) {
            const int cpo = ((ks * 4 + q4) ^ (l15 & 7)) * 8;
            f16x8 sf[4], sflo[4];
            #pragma unroll
            for (int i = 0; i < 4; ++i) {
                sf[i]   = *(const f16x8*)&Xt[(wn + i * 16 + l15) * 64 + cpo];
                sflo[i] = sf[i] * (_Float16)0.00048828125f;   // 2^-11
            }
            #pragma unroll
            for (int s = 0; s < 2; ++s) {
                f16x8 wf[4];
                #pragma unroll
                for (int i = 0; i < 4; ++i)
                    wf[i] = *(const f16x8*)&Wt[s][(wm + i * 16 + l15) * 64 + cpo];
                #pragma unroll
                for (int mt = 0; mt < 4; ++mt)
                    #pragma unroll
                    for (int nt = 0; nt < 4; ++nt)
                        acc[mt][nt] = __builtin_amdgcn_mfma_f32_16x16x32_f16(
                            wf[mt], s ? sflo[nt] : sf[nt], acc[mt][nt], 0, 0, 0);
            }
        }
    }

    #pragma unroll
    for (int mt = 0; mt < 4; ++mt) {
        int o0 = wtile * 128 + wm + mt * 16 + (lane >> 4) * 4;
        #pragma unroll
        for (int nt = 0; nt < 4; ++nt) {
            int row = ntile * 128 + wn + nt * 16 + l15;
            int tb = (row >= bnd) ? tb0 + 1 : tb0;
            int n  = row - tb * NN;
            #pragma unroll
            for (int r = 0; r < 4; ++r)
                Y[((size_t)tb * CC + o0 + r) * NN + n] = acc[mt][nt][r] * scale[o0 + r] + shift[o0 + r];
        }
    }
}

extern "C" void kernel_launch(void* const* d_in, const int* in_sizes, int n_in,
                              void* d_out, int out_size, void* d_ws, size_t ws_size,
                              hipStream_t stream) {
    const float* x    = (const float*)d_in[0];
    const float* q_cw = (const float*)d_in[1];
    const float* q_cb = (const float*)d_in[2];
    const float* q_bg = (const float*)d_in[3];
    const float* q_bb = (const float*)d_in[4];
    const float* q_bm = (const float*)d_in[5];
    const float* q_bv = (const float*)d_in[6];
    const float* k_cw = (const float*)d_in[7];
    const float* k_cb = (const float*)d_in[8];
    const float* k_bg = (const float*)d_in[9];
    const float* k_bb = (const float*)d_in[10];
    const float* k_bm = (const float*)d_in[11];
    const float* k_bv = (const float*)d_in[12];
    const float* v_cw = (const float*)d_in[13];
    const float* v_cb = (const float*)d_in[14];
    const float* v_bg = (const float*)d_in[15];
    const float* v_bb = (const float*)d_in[16];
    const float* v_bm = (const float*)d_in[17];
    const float* v_bv = (const float*)d_in[18];
    const float* p_cw = (const float*)d_in[19];
    const float* p_cb = (const float*)d_in[20];
    const float* p_bg = (const float*)d_in[21];
    const float* p_bb = (const float*)d_in[22];
    const float* p_bm = (const float*)d_in[23];
    const float* p_bv = (const float*)d_in[24];
    const float* pshw = (const float*)d_in[25];
    const float* pllw = (const float*)d_in[26];
    const float* ppb  = (const float*)d_in[27];
    float* out = (float*)d_out;

    // ws map:
    //   [0,26)    XS head spikes (25.7MB)
    //   [27,53)   QS pp spikes
    //   [78,104)  OS attn fp16 (pre/post LIF, in place)
    //   [182,208) KS ; [208,234) VS
    //   [234,238) W2 (4MB) ; then SS/SH
    if (ws_size < (size_t)242 * 1024 * 1024) return;
    char* W = (char*)d_ws;
    u16*   XS = (u16*)W;
    u16*   QS = (u16*)(W + ((size_t)27 << 20));
    u16*   OS = (u16*)(W + ((size_t)78 << 20));
    u16*   KS = (u16*)(W + ((size_t)182 << 20));
    u16*   VS = (u16*)(W + ((size_t)208 << 20));
    u16*   W2 = (u16*)(W + ((size_t)234 << 20));
    float* SS = (float*)(W + ((size_t)238 << 20));            // scale[4][512]
    float* SH = SS + 2048;                                     // shift[4][512]

    k_prep<<<4104, 256, 0, stream>>>(q_cw, k_cw, v_cw, p_cw,
                                     q_cb, q_bg, q_bb, q_bm, q_bv,
                                     k_cb, k_bg, k_bb, k_bm, k_bv,
                                     v_cb, v_bg, v_bb, v_bm, v_bv,
                                     p_cb, p_bg, p_bb, p_bm, p_bv, W2, SS, SH);

    k_head_lif<<<dim3(4, 32, 8), 256, 0, stream>>>(x, XS);

    // fused QKV projection + BN + LIF -> spikes directly (rr-tiled, no padding)
    k_gemm_qkv<<<2352, 256, 0, stream>>>(XS, W2, SS, SH, QS, KS, VS, pshw, pllw, ppb);

    // split attention (R2/R4 config): per (tb,h), 1024 blocks, 4 blocks/CU
    k_attn<<<TBB * NHH, 256, 0, stream>>>(QS, KS, VS, OS);
    k_attn_lif<<<1568, 256, 0, stream>>>((uint4*)OS);

    k_gemm_proj<<<784, 256, 0, stream>>>(OS, W2 + 3 * 524288, SS + 1536, SH + 1536, out);
}